// Round 1
// baseline (30.434 us; speedup 1.0000x reference)
//
#include <hip/hip_runtime.h>

#define B_ 8
#define S_ 1024
#define D_ 2048
#define E_ 2

// ---------- reduction helpers ----------
__device__ inline float wave_reduce_sum(float v) {
    #pragma unroll
    for (int off = 32; off > 0; off >>= 1) v += __shfl_down(v, off, 64);
    return v;
}
__device__ inline float wave_reduce_max(float v) {
    #pragma unroll
    for (int off = 32; off > 0; off >>= 1) v = fmaxf(v, __shfl_down(v, off, 64));
    return v;
}

// ---------- kernel 1: Wsum[e,d] = sum_h W[e,d,h]; bsum[e] = sum_h b[e,h] ----------
// grid = E*D + E blocks of 256 threads; each block reduces one contiguous row of D floats.
__global__ __launch_bounds__(256) void reduce_rows_kernel(
        const float* __restrict__ W, const float* __restrict__ bvec,
        float* __restrict__ Wsum, float* __restrict__ bsum) {
    const int row = blockIdx.x;
    const float* src;
    float* dst;
    if (row < E_ * D_) { src = W + (size_t)row * D_;            dst = Wsum + row; }
    else               { src = bvec + (size_t)(row - E_ * D_) * D_; dst = bsum + (row - E_ * D_); }

    const float4* s4 = (const float4*)src;
    float s = 0.0f;
    for (int i = threadIdx.x; i < D_ / 4; i += 256) {
        float4 v = s4[i];
        s += v.x + v.y + v.z + v.w;
    }
    s = wave_reduce_sum(s);
    __shared__ float lds[4];
    const int wave = threadIdx.x >> 6, lane = threadIdx.x & 63;
    if (lane == 0) lds[wave] = s;
    __syncthreads();
    if (threadIdx.x == 0) *dst = lds[0] + lds[1] + lds[2] + lds[3];
}

// ---------- kernel 2: per-token gate + selected-expert row-sum ----------
// grid = B*S blocks of 256 threads. y[tok] = gate * (dot(x, Wsum[idx]) + bsum[idx])
__global__ __launch_bounds__(256) void token_kernel(
        const float* __restrict__ x, const float* __restrict__ wg,
        const float* __restrict__ Wsum, const float* __restrict__ bsum,
        float* __restrict__ y) {
    const int tok = blockIdx.x;
    const float4* x4  = (const float4*)(x + (size_t)tok * D_);
    const float4* w0  = (const float4*)(Wsum);
    const float4* w1  = (const float4*)(Wsum + D_);
    const float4* wg4 = (const float4*)(wg);   // wg is [D,E=2]: wg4[2i],wg4[2i+1] cover d=4i..4i+3

    float d0 = 0.0f, d1 = 0.0f, g0 = 0.0f, g1 = 0.0f;
    for (int i = threadIdx.x; i < D_ / 4; i += 256) {
        float4 xv = x4[i];
        float4 a  = w0[i];
        float4 c  = w1[i];
        float4 u  = wg4[2 * i];
        float4 v  = wg4[2 * i + 1];
        d0 += xv.x * a.x + xv.y * a.y + xv.z * a.z + xv.w * a.w;
        d1 += xv.x * c.x + xv.y * c.y + xv.z * c.z + xv.w * c.w;
        g0 += xv.x * u.x + xv.y * u.z + xv.z * v.x + xv.w * v.z;
        g1 += xv.x * u.y + xv.y * u.w + xv.z * v.y + xv.w * v.w;
    }
    d0 = wave_reduce_sum(d0);
    d1 = wave_reduce_sum(d1);
    g0 = wave_reduce_sum(g0);
    g1 = wave_reduce_sum(g1);

    __shared__ float lds[4][4];
    const int wave = threadIdx.x >> 6, lane = threadIdx.x & 63;
    if (lane == 0) { lds[wave][0] = d0; lds[wave][1] = d1; lds[wave][2] = g0; lds[wave][3] = g1; }
    __syncthreads();
    if (threadIdx.x == 0) {
        float D0 = lds[0][0] + lds[1][0] + lds[2][0] + lds[3][0];
        float D1 = lds[0][1] + lds[1][1] + lds[2][1] + lds[3][1];
        float G0 = lds[0][2] + lds[1][2] + lds[2][2] + lds[3][2];
        float G1 = lds[0][3] + lds[1][3] + lds[2][3] + lds[3][3];
        // jnp.argmax: first occurrence of max -> idx=1 only on strict G1 > G0
        const int idx = (G1 > G0) ? 1 : 0;
        const float diff = idx ? (G0 - G1) : (G1 - G0);   // l_other - l_chosen, <= 0
        const float gate = 1.0f / (1.0f + __expf(diff) * 0.0f + expf(diff));  // plain expf
        const float dot  = idx ? D1 : D0;
        y[tok] = gate * (dot + bsum[idx]);
    }
}

// ---------- kernel 3: log_softmax over axis=1 (S) ----------
// grid = B blocks of 256 threads; each block handles one row of S=1024.
__global__ __launch_bounds__(256) void logsoftmax_kernel(
        const float* __restrict__ y, float* __restrict__ out) {
    const int b = blockIdx.x;
    const float* row = y + (size_t)b * S_;
    float* orow = out + (size_t)b * S_;

    float m = -3.4e38f;
    for (int i = threadIdx.x; i < S_; i += 256) m = fmaxf(m, row[i]);
    m = wave_reduce_max(m);
    __shared__ float lds[4];
    __shared__ float M_s, L_s;
    const int wave = threadIdx.x >> 6, lane = threadIdx.x & 63;
    if (lane == 0) lds[wave] = m;
    __syncthreads();
    if (threadIdx.x == 0)
        M_s = fmaxf(fmaxf(lds[0], lds[1]), fmaxf(lds[2], lds[3]));
    __syncthreads();
    const float M = M_s;

    float s = 0.0f;
    for (int i = threadIdx.x; i < S_; i += 256) s += expf(row[i] - M);
    s = wave_reduce_sum(s);
    __syncthreads();
    if (lane == 0) lds[wave] = s;
    __syncthreads();
    if (threadIdx.x == 0)
        L_s = M + logf(lds[0] + lds[1] + lds[2] + lds[3]);
    __syncthreads();
    const float lse = L_s;

    for (int i = threadIdx.x; i < S_; i += 256) orow[i] = row[i] - lse;
}

extern "C" void kernel_launch(void* const* d_in, const int* in_sizes, int n_in,
                              void* d_out, int out_size, void* d_ws, size_t ws_size,
                              hipStream_t stream) {
    const float* x  = (const float*)d_in[0];   // [B,S,D]
    const float* wg = (const float*)d_in[1];   // [D,E]
    const float* W  = (const float*)d_in[2];   // [E,D,D]
    const float* bv = (const float*)d_in[3];   // [E,D]
    float* out = (float*)d_out;                // [B,S]

    float* ws   = (float*)d_ws;
    float* Wsum = ws;                  // E*D = 4096 floats
    float* bsum = ws + E_ * D_;        // 2 floats
    float* y    = ws + E_ * D_ + 16;   // B*S = 8192 floats (16B-aligned offset)

    reduce_rows_kernel<<<E_ * D_ + E_, 256, 0, stream>>>(W, bv, Wsum, bsum);
    token_kernel<<<B_ * S_, 256, 0, stream>>>(x, wg, Wsum, bsum, y);
    logsoftmax_kernel<<<B_, 256, 0, stream>>>(y, out);
}